// Round 3
// baseline (1387.628 us; speedup 1.0000x reference)
//
#include <hip/hip_runtime.h>
#include <stdint.h>

typedef short s16x8 __attribute__((ext_vector_type(8)));
typedef float f32x4 __attribute__((ext_vector_type(4)));
typedef unsigned short u16;

__device__ __forceinline__ float bf2f(u16 u) {
  union { unsigned int i; float f; } v; v.i = ((unsigned int)u) << 16; return v.f;
}
__device__ __forceinline__ u16 f2bf(float f) {
  union { float f; unsigned int i; } v; v.f = f;
  unsigned int i = v.i;
  unsigned int r = (i + 0x7fffu + ((i >> 16) & 1u)) >> 16;
  return (u16)r;
}

// Load 8 consecutive elements as bf16 fragment, from either fp32 or bf16 data.
__device__ __forceinline__ s16x8 load8(const void* p, size_t idx, int isf32) {
  s16x8 r;
  if (isf32) {
    const float* f = (const float*)p + idx;
    f32x4 a = *(const f32x4*)f;
    f32x4 b = *(const f32x4*)(f + 4);
#pragma unroll
    for (int j = 0; j < 4; j++) {
      r[j] = (short)f2bf(a[j]);
      r[4 + j] = (short)f2bf(b[j]);
    }
  } else {
    r = *(const s16x8*)((const u16*)p + idx);
  }
  return r;
}

__device__ __forceinline__ float loadf(const void* p, size_t idx, int isf32) {
  return isf32 ? ((const float*)p)[idx] : bf2f(((const u16*)p)[idx]);
}

// RoPE on a 4-pair bf16 fragment with fp32 cos/sin.
__device__ __forceinline__ s16x8 rope8(s16x8 x, const float* c, const float* s) {
  s16x8 out;
#pragma unroll
  for (int j = 0; j < 4; j++) {
    float x1 = bf2f((u16)x[2 * j]);
    float x2 = bf2f((u16)x[2 * j + 1]);
    out[2 * j] = (short)f2bf(x1 * c[j] - x2 * s[j]);
    out[2 * j + 1] = (short)f2bf(x1 * s[j] + x2 * c[j]);
  }
  return out;
}

// ---------------------------------------------------------------------------
// Dtype detector: bf16 N(0,1) data never has exponent-field >= 0xF0; fp32
// data read as u16 has uniformly random exponent bits in the low halves.
// flags[0] = 1 if inputs are fp32, else 0.  flags[1] = constant 0.
// ---------------------------------------------------------------------------
__global__ void detect_dtype(const u16* __restrict__ x, int* __restrict__ flags) {
  int cnt = 0;
  for (int i = threadIdx.x; i < 4096; i += 64) {
    int e = (x[i] >> 7) & 0xFF;
    if (e >= 0xF0) cnt++;
  }
  unsigned long long any = __ballot(cnt > 0);
  if (threadIdx.x == 0) {
    flags[0] = (any != 0ull) ? 1 : 0;
    flags[1] = 0;
  }
}

// ---------------------------------------------------------------------------
// C[M,N] = A[M,K] * B[K,N] + bias[N]  (bf16 MFMA, fp32 accum, bf16 C out)
// A, B, bias may each be fp32 or bf16 per flags. A offset in elements.
// block 256 = 4 waves, 128x128 tile, BK=32, MFMA 16x16x32 bf16
// ---------------------------------------------------------------------------
__global__ __launch_bounds__(256) void gemm_xw_bias(
    const void* __restrict__ A, size_t aOff, const int* __restrict__ aF32p,
    const void* __restrict__ B, const void* __restrict__ bias,
    const int* __restrict__ wF32p, u16* __restrict__ C, int N, int K) {
  __shared__ __attribute__((aligned(16))) u16 As[128 * 40];
  __shared__ __attribute__((aligned(16))) u16 Bs[128 * 40];
  const int af32 = *aF32p, wf32 = *wF32p;
  const int tid = threadIdx.x;
  const int wave = tid >> 6, lane = tid & 63, quad = lane >> 4, l16 = lane & 15;
  const int m0 = blockIdx.y * 128, n0 = blockIdx.x * 128;
  const int wm = (wave & 1) * 64, wn = (wave >> 1) * 64;
  f32x4 acc[4][4];
#pragma unroll
  for (int i = 0; i < 4; i++)
#pragma unroll
    for (int j = 0; j < 4; j++) acc[i][j] = (f32x4){0.f, 0.f, 0.f, 0.f};

  for (int kb = 0; kb < K; kb += 32) {
    __syncthreads();
    // A tile: 128 rows x 32 k, k-contiguous
#pragma unroll
    for (int i = 0; i < 2; i++) {
      int c = tid + i * 256;
      int row = c >> 2, k8 = c & 3;
      s16x8 av = load8(A, aOff + (size_t)(m0 + row) * K + kb + k8 * 8, af32);
      *(s16x8*)(As + row * 40 + k8 * 8) = av;
    }
    // B tile: 32 k-rows x 128 n, n-contiguous loads, transpose into Bs[n][k]
    {
      int kr = tid >> 3, c16 = (tid & 7) * 16;
      size_t base = (size_t)(kb + kr) * N + n0 + c16;
      s16x8 b0 = load8(B, base, wf32);
      s16x8 b1 = load8(B, base + 8, wf32);
#pragma unroll
      for (int j = 0; j < 8; j++) {
        Bs[(c16 + j) * 40 + kr] = (u16)b0[j];
        Bs[(c16 + 8 + j) * 40 + kr] = (u16)b1[j];
      }
    }
    __syncthreads();
    s16x8 af[4], bfr[4];
#pragma unroll
    for (int t = 0; t < 4; t++) {
      af[t] = *(const s16x8*)(As + (wm + t * 16 + l16) * 40 + quad * 8);
      bfr[t] = *(const s16x8*)(Bs + (wn + t * 16 + l16) * 40 + quad * 8);
    }
#pragma unroll
    for (int mt = 0; mt < 4; mt++)
#pragma unroll
      for (int nt = 0; nt < 4; nt++)
        acc[mt][nt] = __builtin_amdgcn_mfma_f32_16x16x32_bf16(
            af[mt], bfr[nt], acc[mt][nt], 0, 0, 0);
  }
  // epilogue: C/D layout col=lane&15, row=quad*4+reg
#pragma unroll
  for (int nt = 0; nt < 4; nt++) {
    int col = n0 + wn + nt * 16 + l16;
    float bv = loadf(bias, col, wf32);
#pragma unroll
    for (int mt = 0; mt < 4; mt++) {
#pragma unroll
      for (int r = 0; r < 4; r++) {
        int row = m0 + wm + mt * 16 + quad * 4 + r;
        C[(size_t)row * N + col] = f2bf(acc[mt][nt][r] + bv);
      }
    }
  }
}

// ---------------------------------------------------------------------------
// Causal flash attention for ONE batch: qkv[2048][3072] bf16 (Q|K|V, C=1024).
// block = 4 waves, 64 Q rows (16/wave), 32-key chunks, RoPE in-register.
// Writes y[2048][1024] bf16.
// ---------------------------------------------------------------------------
__global__ __launch_bounds__(256) void attn_kernel(
    const u16* __restrict__ qkv, const void* __restrict__ cost,
    const void* __restrict__ sint, const int* __restrict__ tF32p,
    u16* __restrict__ y) {
  __shared__ __attribute__((aligned(16))) u16 vt[64 * 40];       // V^T [d][s]
  __shared__ __attribute__((aligned(16))) u16 plds[4][16 * 40];  // per-wave P
  const int tf32 = *tF32p;
  const int tid = threadIdx.x;
  const int wave = tid >> 6, lane = tid & 63, quad = lane >> 4, l16 = lane & 15;
  const int qt = blockIdx.x & 31, h = blockIdx.x >> 5;
  const int qb = qt * 64;
  const float NEG = -3.0e4f;
  const float LOG2E = 1.4426950408889634f;

  // Q fragments (A-layout: m=l16, k=quad*8+j) + RoPE
  const int tq = qb + wave * 16 + l16;
  const u16* qrow = qkv + (size_t)tq * 3072 + h * 64;
  s16x8 qa0 = *(const s16x8*)(qrow + quad * 8);
  s16x8 qa1 = *(const s16x8*)(qrow + 32 + quad * 8);
  {
    float c[4], s[4];
#pragma unroll
    for (int j = 0; j < 4; j++) {
      c[j] = loadf(cost, (size_t)tq * 32 + quad * 4 + j, tf32);
      s[j] = loadf(sint, (size_t)tq * 32 + quad * 4 + j, tf32);
    }
    qa0 = rope8(qa0, c, s);
#pragma unroll
    for (int j = 0; j < 4; j++) {
      c[j] = loadf(cost, (size_t)tq * 32 + 16 + quad * 4 + j, tf32);
      s[j] = loadf(sint, (size_t)tq * 32 + 16 + quad * 4 + j, tf32);
    }
    qa1 = rope8(qa1, c, s);
  }

  f32x4 o[4];
#pragma unroll
  for (int dt = 0; dt < 4; dt++) o[dt] = (f32x4){0.f, 0.f, 0.f, 0.f};
  float m_r[4], l_r[4];
#pragma unroll
  for (int r = 0; r < 4; r++) { m_r[r] = NEG; l_r[r] = 0.f; }
  const int qrow_base = qb + wave * 16 + quad * 4;

  for (int sb = 0; sb <= qb + 32; sb += 32) {
    __syncthreads();
    {  // stage V chunk [32 s][64 d] transposed into vt[d][s]
      int sl = tid >> 3, c8 = tid & 7;
      s16x8 vv = *(const s16x8*)(qkv + (size_t)(sb + sl) * 3072 + 2048 +
                                 h * 64 + c8 * 8);
#pragma unroll
      for (int j = 0; j < 8; j++) vt[(c8 * 8 + j) * 40 + sl] = (u16)vv[j];
    }
    __syncthreads();

    // S = Q K^T for two 16-key tiles (B-layout: n=l16 -> key, k -> d)
    f32x4 S[2];
#pragma unroll
    for (int t2 = 0; t2 < 2; t2++) {
      int s = sb + t2 * 16 + l16;
      const u16* krow = qkv + (size_t)s * 3072 + 1024 + h * 64;
      s16x8 k0 = *(const s16x8*)(krow + quad * 8);
      s16x8 k1 = *(const s16x8*)(krow + 32 + quad * 8);
      float cc[4], ss[4];
#pragma unroll
      for (int j = 0; j < 4; j++) {
        cc[j] = loadf(cost, (size_t)s * 32 + quad * 4 + j, tf32);
        ss[j] = loadf(sint, (size_t)s * 32 + quad * 4 + j, tf32);
      }
      k0 = rope8(k0, cc, ss);
#pragma unroll
      for (int j = 0; j < 4; j++) {
        cc[j] = loadf(cost, (size_t)s * 32 + 16 + quad * 4 + j, tf32);
        ss[j] = loadf(sint, (size_t)s * 32 + 16 + quad * 4 + j, tf32);
      }
      k1 = rope8(k1, cc, ss);
      f32x4 a = (f32x4){0.f, 0.f, 0.f, 0.f};
      a = __builtin_amdgcn_mfma_f32_16x16x32_bf16(qa0, k0, a, 0, 0, 0);
      a = __builtin_amdgcn_mfma_f32_16x16x32_bf16(qa1, k1, a, 0, 0, 0);
      S[t2] = a;
    }
    // scale + causal mask; row max over 16 lanes of the quad
    float mx[4];
#pragma unroll
    for (int r = 0; r < 4; r++) {
      int qi = qrow_base + r;
#pragma unroll
      for (int t2 = 0; t2 < 2; t2++) {
        int si = sb + t2 * 16 + l16;
        float v = S[t2][r] * 0.125f;
        S[t2][r] = (si <= qi) ? v : NEG;
      }
      mx[r] = fmaxf(S[0][r], S[1][r]);
    }
#pragma unroll
    for (int off = 8; off; off >>= 1)
#pragma unroll
      for (int r = 0; r < 4; r++) mx[r] = fmaxf(mx[r], __shfl_xor(mx[r], off));

    float alpha[4];
#pragma unroll
    for (int r = 0; r < 4; r++) {
      float mn = fmaxf(m_r[r], mx[r]);
      alpha[r] = exp2f((m_r[r] - mn) * LOG2E);
      m_r[r] = mn;
    }
    float rs[4];
#pragma unroll
    for (int r = 0; r < 4; r++) {
      float p0 = exp2f((S[0][r] - m_r[r]) * LOG2E);
      float p1 = exp2f((S[1][r] - m_r[r]) * LOG2E);
      S[0][r] = p0; S[1][r] = p1;
      rs[r] = p0 + p1;
    }
#pragma unroll
    for (int off = 8; off; off >>= 1)
#pragma unroll
      for (int r = 0; r < 4; r++) rs[r] += __shfl_xor(rs[r], off);
#pragma unroll
    for (int r = 0; r < 4; r++) l_r[r] = l_r[r] * alpha[r] + rs[r];

    // P: C-layout -> LDS -> A-layout
    u16* P = plds[wave];
#pragma unroll
    for (int t2 = 0; t2 < 2; t2++)
#pragma unroll
      for (int r = 0; r < 4; r++)
        P[(quad * 4 + r) * 40 + t2 * 16 + l16] = f2bf(S[t2][r]);
    __syncthreads();
    s16x8 pa = *(const s16x8*)(P + l16 * 40 + quad * 8);

#pragma unroll
    for (int dt = 0; dt < 4; dt++) {
#pragma unroll
      for (int r = 0; r < 4; r++) o[dt][r] *= alpha[r];
      s16x8 vb = *(const s16x8*)(vt + (dt * 16 + l16) * 40 + quad * 8);
      o[dt] = __builtin_amdgcn_mfma_f32_16x16x32_bf16(pa, vb, o[dt], 0, 0, 0);
    }
  }

#pragma unroll
  for (int r = 0; r < 4; r++) l_r[r] = 1.0f / fmaxf(l_r[r], 1e-30f);
#pragma unroll
  for (int dt = 0; dt < 4; dt++) {
#pragma unroll
    for (int r = 0; r < 4; r++) {
      int trow = qrow_base + r;
      y[(size_t)trow * 1024 + h * 64 + dt * 16 + l16] =
          f2bf(o[dt][r] * l_r[r]);
    }
  }
}

// Final store: bf16 scratch -> output buffer (fp32 or bf16 per flag).
__global__ __launch_bounds__(256) void store_out(const u16* __restrict__ src,
                                                 void* __restrict__ dst,
                                                 const int* __restrict__ fp) {
  const int isf32 = *fp;
  size_t i = ((size_t)blockIdx.x * 256 + threadIdx.x) * 8;
  s16x8 v = *(const s16x8*)(src + i);
  if (isf32) {
    float* d = (float*)dst + i;
#pragma unroll
    for (int j = 0; j < 8; j++) d[j] = bf2f((u16)v[j]);
  } else {
    *(s16x8*)((u16*)dst + i) = v;
  }
}

extern "C" void kernel_launch(void* const* d_in, const int* in_sizes, int n_in,
                              void* d_out, int out_size, void* d_ws,
                              size_t ws_size, hipStream_t stream) {
  const void* x = d_in[0];      // [2,2048,1024]
  const void* Wqkv = d_in[1];   // [1024,3072]
  const void* bqkv = d_in[2];   // [3072]
  const void* Wproj = d_in[3];  // [1024,1024]
  const void* bproj = d_in[4];  // [1024]
  const void* cost = d_in[5];   // [2048,32]
  const void* sint = d_in[6];   // [2048,32]

  int* flags = (int*)d_ws;                      // [0]=isf32, [1]=0
  u16* qkv = (u16*)d_ws + 128;                  // 2048*3072 bf16 = 12.58 MB
  u16* proj = qkv;                              // reuse after attention
  u16* yb = (u16*)d_out;                        // y scratch lives in d_out

  detect_dtype<<<1, 64, 0, stream>>>((const u16*)x, flags);

  for (int b = 0; b < 2; b++) {
    // qkv_b = x_b @ Wqkv + bqkv
    gemm_xw_bias<<<dim3(3072 / 128, 2048 / 128), 256, 0, stream>>>(
        x, (size_t)b * 2048 * 1024, &flags[0], Wqkv, bqkv, &flags[0], qkv,
        3072, 1024);
    // y_b = attention(qkv_b)
    attn_kernel<<<dim3(16 * (2048 / 64)), 256, 0, stream>>>(
        qkv, cost, sint, &flags[0], yb + (size_t)b * 2048 * 1024);
  }
  // proj = y @ Wproj + bproj  (y is bf16 scratch in d_out)
  gemm_xw_bias<<<dim3(1024 / 128, 4096 / 128), 256, 0, stream>>>(
      yb, 0, &flags[1], Wproj, bproj, &flags[0], proj, 1024, 1024);
  // d_out = proj (converted to output dtype)
  store_out<<<dim3((4096 * 1024) / (256 * 8)), 256, 0, stream>>>(proj, d_out,
                                                                 &flags[0]);
}

// Round 4
// 319.026 us; speedup vs baseline: 4.3496x; 4.3496x over previous
//
#include <hip/hip_runtime.h>
#include <stdint.h>

typedef short s16x8 __attribute__((ext_vector_type(8)));
typedef float f32x4 __attribute__((ext_vector_type(4)));
typedef unsigned short u16;

__device__ __forceinline__ float bf2f(u16 u) {
  union { unsigned int i; float f; } v; v.i = ((unsigned int)u) << 16; return v.f;
}
__device__ __forceinline__ u16 f2bf(float f) {
  union { float f; unsigned int i; } v; v.f = f;
  unsigned int i = v.i;
  unsigned int r = (i + 0x7fffu + ((i >> 16) & 1u)) >> 16;
  return (u16)r;
}

// Load 8 consecutive elements as bf16 fragment, from fp32 or bf16 data.
__device__ __forceinline__ s16x8 load8(const void* p, size_t idx, int isf32) {
  s16x8 r;
  if (isf32) {
    const float* f = (const float*)p + idx;
    f32x4 a = *(const f32x4*)f;
    f32x4 b = *(const f32x4*)(f + 4);
#pragma unroll
    for (int j = 0; j < 4; j++) {
      r[j] = (short)f2bf(a[j]);
      r[4 + j] = (short)f2bf(b[j]);
    }
  } else {
    r = *(const s16x8*)((const u16*)p + idx);
  }
  return r;
}

__device__ __forceinline__ float loadf(const void* p, size_t idx, int isf32) {
  return isf32 ? ((const float*)p)[idx] : bf2f(((const u16*)p)[idx]);
}

// ---------------------------------------------------------------------------
// Dtype detector (proven R3): flags[0]=1 if inputs fp32, flags[1]=0 always.
// ---------------------------------------------------------------------------
__global__ void detect_dtype(const u16* __restrict__ x, int* __restrict__ flags) {
  int cnt = 0;
  for (int i = threadIdx.x; i < 4096; i += 64) {
    int e = (x[i] >> 7) & 0xFF;
    if (e >= 0xF0) cnt++;
  }
  unsigned long long any = __ballot(cnt > 0);
  if (threadIdx.x == 0) {
    flags[0] = (any != 0ull) ? 1 : 0;
    flags[1] = 0;
  }
}

// ---------------------------------------------------------------------------
// W[K][N] (fp32/bf16) -> WT[N][K] bf16. u32-packed LDS transpose:
// loader packs k-pairs into u32 -> conflict-free column gather on read.
// ---------------------------------------------------------------------------
__global__ __launch_bounds__(256) void transposeW(const void* __restrict__ W,
                                                  const int* __restrict__ fp,
                                                  u16* __restrict__ WT, int K,
                                                  int N) {
  __shared__ unsigned int tile32[32 * 66];  // [k_pair][n], 64x64 bf16 tile
  const int f = *fp;
  const int tid = threadIdx.x;
  const int nb = blockIdx.x * 64, kb = blockIdx.y * 64;
  {  // load 2 k-rows x 8 n per thread, pack pairs along k
    int a = tid >> 3, c8 = tid & 7;
    s16x8 r0 = load8(W, (size_t)(kb + 2 * a) * N + nb + c8 * 8, f);
    s16x8 r1 = load8(W, (size_t)(kb + 2 * a + 1) * N + nb + c8 * 8, f);
#pragma unroll
    for (int j = 0; j < 8; j++) {
      unsigned int pk = (unsigned int)(u16)r0[j] | ((unsigned int)(u16)r1[j] << 16);
      tile32[a * 66 + c8 * 8 + j] = pk;
    }
  }
  __syncthreads();
#pragma unroll
  for (int i = 0; i < 2; i++) {  // out: 64 n-rows x 64 k
    int idx = tid + i * 256;
    int n = idx >> 3, c8 = idx & 7;
    s16x8 v;
#pragma unroll
    for (int w = 0; w < 4; w++) {
      unsigned int pk = tile32[(c8 * 4 + w) * 66 + n];
      v[2 * w] = (short)(u16)(pk & 0xFFFF);
      v[2 * w + 1] = (short)(u16)(pk >> 16);
    }
    *(s16x8*)(WT + (size_t)(nb + n) * K + kb + c8 * 8) = v;
  }
}

// ---------------------------------------------------------------------------
// Fused GEMM: C[M,N] = A[M,K] @ B + bias, bf16 MFMA, fp32 accum.
//  btMode=1: B = bf16 [N][K] (pre-transposed, vector staging)
//  btMode=0: B = [K][N] fp32/bf16 (scalar-scatter staging, R3-proven)
//  ropeMode=1 (qkv GEMM, N=3072): cols<2048 get RoPE (pair via shfl_xor),
//   cols>=2048 (V) are written transposed to vT[((b*16+h)*64+d)][2048] only.
// block 256 = 4 waves, 128x128 tile, BK=32, MFMA 16x16x32 bf16.
// ---------------------------------------------------------------------------
__global__ __launch_bounds__(256) void gemm_fused(
    const void* __restrict__ A, size_t aOff, const int* __restrict__ aF32p,
    const void* __restrict__ B, const int* __restrict__ inF32p, int btMode,
    const void* __restrict__ bias, u16* __restrict__ C, u16* __restrict__ vT,
    int ropeMode, const void* __restrict__ cost, const void* __restrict__ sint,
    int N, int K) {
  __shared__ __attribute__((aligned(16))) u16 As[128 * 40];
  __shared__ __attribute__((aligned(16))) u16 Bs[128 * 40];
  const int af32 = *aF32p, inf32 = *inF32p;
  const int tid = threadIdx.x;
  const int wave = tid >> 6, lane = tid & 63, quad = lane >> 4, l16 = lane & 15;
  const int m0 = blockIdx.y * 128, n0 = blockIdx.x * 128;
  const int wm = (wave & 1) * 64, wn = (wave >> 1) * 64;
  f32x4 acc[4][4];
#pragma unroll
  for (int i = 0; i < 4; i++)
#pragma unroll
    for (int j = 0; j < 4; j++) acc[i][j] = (f32x4){0.f, 0.f, 0.f, 0.f};

  for (int kb = 0; kb < K; kb += 32) {
    __syncthreads();
#pragma unroll
    for (int i = 0; i < 2; i++) {  // A tile, k-contiguous
      int c = tid + i * 256;
      int row = c >> 2, k8 = c & 3;
      s16x8 av = load8(A, aOff + (size_t)(m0 + row) * K + kb + k8 * 8, af32);
      *(s16x8*)(As + row * 40 + k8 * 8) = av;
    }
    if (btMode) {  // B pre-transposed bf16 [N][K]: vector staging
#pragma unroll
      for (int i = 0; i < 2; i++) {
        int c = tid + i * 256;
        int row = c >> 2, k8 = c & 3;
        *(s16x8*)(Bs + row * 40 + k8 * 8) =
            *(const s16x8*)((const u16*)B + (size_t)(n0 + row) * K + kb + k8 * 8);
      }
    } else {  // B native [K][N]: n-contiguous loads, scalar transpose scatter
      int kr = tid >> 3, c16 = (tid & 7) * 16;
      size_t base = (size_t)(kb + kr) * N + n0 + c16;
      s16x8 b0 = load8(B, base, inf32);
      s16x8 b1 = load8(B, base + 8, inf32);
#pragma unroll
      for (int j = 0; j < 8; j++) {
        Bs[(c16 + j) * 40 + kr] = (u16)b0[j];
        Bs[(c16 + 8 + j) * 40 + kr] = (u16)b1[j];
      }
    }
    __syncthreads();
    s16x8 af[4], bfr[4];
#pragma unroll
    for (int t = 0; t < 4; t++) {
      af[t] = *(const s16x8*)(As + (wm + t * 16 + l16) * 40 + quad * 8);
      bfr[t] = *(const s16x8*)(Bs + (wn + t * 16 + l16) * 40 + quad * 8);
    }
#pragma unroll
    for (int mt = 0; mt < 4; mt++)
#pragma unroll
      for (int nt = 0; nt < 4; nt++)
        acc[mt][nt] = __builtin_amdgcn_mfma_f32_16x16x32_bf16(
            af[mt], bfr[nt], acc[mt][nt], 0, 0, 0);
  }
  // epilogue: C/D layout col=lane&15, row=quad*4+reg
#pragma unroll
  for (int nt = 0; nt < 4; nt++) {
    int col = n0 + wn + nt * 16 + l16;
    float bv = loadf(bias, col, inf32);
    if (ropeMode && col >= 2048) {  // V: transposed write only
      int d = col & 63, hv = (col - 2048) >> 6;
#pragma unroll
      for (int mt = 0; mt < 4; mt++)
#pragma unroll
        for (int r = 0; r < 4; r++) {
          int row = m0 + wm + mt * 16 + quad * 4 + r;
          float val = acc[mt][nt][r] + bv;
          vT[(((size_t)(row >> 11) * 16 + hv) * 64 + d) * 2048 + (row & 2047)] =
              f2bf(val);
        }
    } else if (ropeMode) {  // Q/K: RoPE via column-pair shfl
      int j = (col & 63) >> 1, odd = col & 1;
#pragma unroll
      for (int mt = 0; mt < 4; mt++)
#pragma unroll
        for (int r = 0; r < 4; r++) {
          int row = m0 + wm + mt * 16 + quad * 4 + r, t = row & 2047;
          float cv = loadf(cost, (size_t)t * 32 + j, inf32);
          float sv = loadf(sint, (size_t)t * 32 + j, inf32);
          float val = acc[mt][nt][r] + bv;
          float pr = __shfl_xor(val, 1);
          float res = odd ? (pr * sv + val * cv) : (val * cv - pr * sv);
          C[(size_t)row * N + col] = f2bf(res);
        }
    } else {
#pragma unroll
      for (int mt = 0; mt < 4; mt++)
#pragma unroll
        for (int r = 0; r < 4; r++) {
          int row = m0 + wm + mt * 16 + quad * 4 + r;
          C[(size_t)row * N + col] = f2bf(acc[mt][nt][r] + bv);
        }
    }
  }
}

// ---------------------------------------------------------------------------
// Causal flash attention. qkv rows hold RoPE'd Q|K (V third unused);
// vT[(b*16+h)*64+d][2048] holds V^T. Block = pair (qt, 31-qt) of 64-row
// Q-tiles (uniform 33 chunks/block); 64-key chunks staged in LDS.
// grid: (16 pairs, nbh). Writes y[rows][1024] bf16.
// ---------------------------------------------------------------------------
__global__ __launch_bounds__(256) void attn_kernel(const u16* __restrict__ qkv,
                                                   const u16* __restrict__ vT,
                                                   u16* __restrict__ y) {
  __shared__ __attribute__((aligned(16))) u16 Qs[64 * 72];
  __shared__ __attribute__((aligned(16))) u16 Ks[64 * 72];
  __shared__ __attribute__((aligned(16))) u16 Vt[64 * 72];
  __shared__ __attribute__((aligned(16))) u16 Pl[4][16 * 72];
  const int tid = threadIdx.x;
  const int wave = tid >> 6, lane = tid & 63, quad = lane >> 4, l16 = lane & 15;
  const int pair = blockIdx.x;  // 0..15
  const int bh = blockIdx.y, h = bh & 15;
  const size_t rb = (size_t)(bh >> 4) * 2048;
  const float NEG = -3.0e4f, LOG2E = 1.4426950408889634f;

  for (int half = 0; half < 2; half++) {
    const int qt = half ? (31 - pair) : pair;
    const int qb = qt * 64;
    __syncthreads();  // Qs reuse guard
#pragma unroll
    for (int i = 0; i < 2; i++) {  // stage Q tile (coalesced)
      int idx = tid + i * 256, row = idx >> 3, c8 = idx & 7;
      *(s16x8*)(Qs + row * 72 + c8 * 8) =
          *(const s16x8*)(qkv + (rb + qb + row) * 3072 + h * 64 + c8 * 8);
    }
    __syncthreads();
    s16x8 qa0 = *(const s16x8*)(Qs + (wave * 16 + l16) * 72 + quad * 8);
    s16x8 qa1 = *(const s16x8*)(Qs + (wave * 16 + l16) * 72 + 32 + quad * 8);

    f32x4 o[4];
#pragma unroll
    for (int dt = 0; dt < 4; dt++) o[dt] = (f32x4){0.f, 0.f, 0.f, 0.f};
    float m_r[4], l_r[4];
#pragma unroll
    for (int r = 0; r < 4; r++) { m_r[r] = NEG; l_r[r] = 0.f; }
    const int qrow = qb + wave * 16 + quad * 4;  // + r

    for (int sb = 0; sb <= qb; sb += 64) {
      __syncthreads();  // Ks/Vt reuse guard
#pragma unroll
      for (int i = 0; i < 2; i++) {  // stage K + V^T chunk (coalesced)
        int idx = tid + i * 256, row = idx >> 3, c8 = idx & 7;
        *(s16x8*)(Ks + row * 72 + c8 * 8) = *(const s16x8*)(
            qkv + (rb + sb + row) * 3072 + 1024 + h * 64 + c8 * 8);
        *(s16x8*)(Vt + row * 72 + c8 * 8) =
            *(const s16x8*)(vT + ((size_t)bh * 64 + row) * 2048 + sb + c8 * 8);
      }
      __syncthreads();

      f32x4 S[4];
#pragma unroll
      for (int kf = 0; kf < 4; kf++) {
        s16x8 k0 = *(const s16x8*)(Ks + (kf * 16 + l16) * 72 + quad * 8);
        s16x8 k1 = *(const s16x8*)(Ks + (kf * 16 + l16) * 72 + 32 + quad * 8);
        f32x4 a = (f32x4){0.f, 0.f, 0.f, 0.f};
        a = __builtin_amdgcn_mfma_f32_16x16x32_bf16(qa0, k0, a, 0, 0, 0);
        a = __builtin_amdgcn_mfma_f32_16x16x32_bf16(qa1, k1, a, 0, 0, 0);
        S[kf] = a;
      }
      float mx[4];
      if (sb == qb) {  // diagonal chunk: scale + causal mask
#pragma unroll
        for (int r = 0; r < 4; r++) {
          int qi = qrow + r;
#pragma unroll
          for (int kf = 0; kf < 4; kf++) {
            int si = sb + kf * 16 + l16;
            float v = S[kf][r] * 0.125f;
            S[kf][r] = (si <= qi) ? v : NEG;
          }
        }
      } else {
#pragma unroll
        for (int r = 0; r < 4; r++)
#pragma unroll
          for (int kf = 0; kf < 4; kf++) S[kf][r] *= 0.125f;
      }
#pragma unroll
      for (int r = 0; r < 4; r++)
        mx[r] = fmaxf(fmaxf(S[0][r], S[1][r]), fmaxf(S[2][r], S[3][r]));
#pragma unroll
      for (int off = 8; off; off >>= 1)
#pragma unroll
        for (int r = 0; r < 4; r++) mx[r] = fmaxf(mx[r], __shfl_xor(mx[r], off));

      float alpha[4], rs[4];
#pragma unroll
      for (int r = 0; r < 4; r++) {
        float mn = fmaxf(m_r[r], mx[r]);
        alpha[r] = exp2f((m_r[r] - mn) * LOG2E);
        m_r[r] = mn;
        float acc_p = 0.f;
#pragma unroll
        for (int kf = 0; kf < 4; kf++) {
          float p = exp2f((S[kf][r] - mn) * LOG2E);
          S[kf][r] = p;
          acc_p += p;
        }
        rs[r] = acc_p;
      }
#pragma unroll
      for (int off = 8; off; off >>= 1)
#pragma unroll
        for (int r = 0; r < 4; r++) rs[r] += __shfl_xor(rs[r], off);
#pragma unroll
      for (int r = 0; r < 4; r++) l_r[r] = l_r[r] * alpha[r] + rs[r];

      // P: C-layout -> LDS -> A-layout (per-wave buffer)
      u16* P = Pl[wave];
#pragma unroll
      for (int kf = 0; kf < 4; kf++)
#pragma unroll
        for (int r = 0; r < 4; r++)
          P[(quad * 4 + r) * 72 + kf * 16 + l16] = f2bf(S[kf][r]);
      __syncthreads();
      s16x8 pa0 = *(const s16x8*)(P + l16 * 72 + quad * 8);
      s16x8 pa1 = *(const s16x8*)(P + l16 * 72 + 32 + quad * 8);

#pragma unroll
      for (int dt = 0; dt < 4; dt++) {
#pragma unroll
        for (int r = 0; r < 4; r++) o[dt][r] *= alpha[r];
        s16x8 vb0 = *(const s16x8*)(Vt + (dt * 16 + l16) * 72 + quad * 8);
        s16x8 vb1 = *(const s16x8*)(Vt + (dt * 16 + l16) * 72 + 32 + quad * 8);
        o[dt] = __builtin_amdgcn_mfma_f32_16x16x32_bf16(pa0, vb0, o[dt], 0, 0, 0);
        o[dt] = __builtin_amdgcn_mfma_f32_16x16x32_bf16(pa1, vb1, o[dt], 0, 0, 0);
      }
    }

    float inv[4];
#pragma unroll
    for (int r = 0; r < 4; r++) inv[r] = 1.0f / fmaxf(l_r[r], 1e-30f);
#pragma unroll
    for (int dt = 0; dt < 4; dt++)
#pragma unroll
      for (int r = 0; r < 4; r++)
        y[(rb + qrow + r) * 1024 + h * 64 + dt * 16 + l16] =
            f2bf(o[dt][r] * inv[r]);
  }
}

// Final store: bf16 scratch -> output buffer (fp32 or bf16 per flag).
__global__ __launch_bounds__(256) void store_out(const u16* __restrict__ src,
                                                 void* __restrict__ dst,
                                                 const int* __restrict__ fp) {
  const int isf32 = *fp;
  size_t i = ((size_t)blockIdx.x * 256 + threadIdx.x) * 8;
  s16x8 v = *(const s16x8*)(src + i);
  if (isf32) {
    float* d = (float*)dst + i;
#pragma unroll
    for (int j = 0; j < 8; j++) d[j] = bf2f((u16)v[j]);
  } else {
    *(s16x8*)((u16*)dst + i) = v;
  }
}

extern "C" void kernel_launch(void* const* d_in, const int* in_sizes, int n_in,
                              void* d_out, int out_size, void* d_ws,
                              size_t ws_size, hipStream_t stream) {
  const void* x = d_in[0];      // [2,2048,1024]
  const void* Wqkv = d_in[1];   // [1024,3072]
  const void* bqkv = d_in[2];   // [3072]
  const void* Wproj = d_in[3];  // [1024,1024]
  const void* bproj = d_in[4];  // [1024]
  const void* cost = d_in[5];   // [2048,32]
  const void* sint = d_in[6];   // [2048,32]

  int* flags = (int*)d_ws;  // [0]=isf32 inputs, [1]=0 (bf16 marker)
  u16* yb = (u16*)d_out;                        // y bf16 scratch [4096*1024]
  u16* vT = (u16*)d_out + (size_t)4096 * 1024;  // V^T bf16 (upper half)

  detect_dtype<<<1, 64, 0, stream>>>((const u16*)x, flags);

  const size_t tierA_need = 256 + ((size_t)3072 * 1024 + (size_t)1024 * 1024 +
                                   (size_t)4096 * 3072) * 2;
  if (ws_size >= tierA_need) {
    // ---- Tier A: pre-transposed bf16 weights, combined batches ----
    u16* WqkvT = (u16*)d_ws + 128;                  // [3072][1024]
    u16* WprojT = WqkvT + (size_t)3072 * 1024;      // [1024][1024]
    u16* qkv = WprojT + (size_t)1024 * 1024;        // [4096][3072]
    u16* proj = qkv;                                // reuse after attention

    transposeW<<<dim3(48, 16), 256, 0, stream>>>(Wqkv, flags, WqkvT, 1024, 3072);
    transposeW<<<dim3(16, 16), 256, 0, stream>>>(Wproj, flags, WprojT, 1024, 1024);
    gemm_fused<<<dim3(24, 32), 256, 0, stream>>>(
        x, 0, &flags[0], WqkvT, &flags[0], 1, bqkv, qkv, vT, 1, cost, sint,
        3072, 1024);
    attn_kernel<<<dim3(16, 32), 256, 0, stream>>>(qkv, vT, yb);
    gemm_fused<<<dim3(8, 32), 256, 0, stream>>>(
        yb, 0, &flags[1], WprojT, &flags[0], 1, bproj, proj, (u16*)nullptr, 0,
        cost, sint, 1024, 1024);
    store_out<<<dim3(2048), 256, 0, stream>>>(proj, d_out, &flags[0]);
  } else {
    // ---- Tier B: R3-proven scatter GEMM, per-batch qkv (12.6 MB ws) ----
    u16* qkv = (u16*)d_ws + 128;  // [2048][3072] per batch
    u16* proj = qkv;
    for (int b = 0; b < 2; b++) {
      gemm_fused<<<dim3(24, 16), 256, 0, stream>>>(
          x, (size_t)b * 2048 * 1024, &flags[0], Wqkv, &flags[0], 0, bqkv, qkv,
          vT, 1, cost, sint, 3072, 1024);
      attn_kernel<<<dim3(16, 16), 256, 0, stream>>>(
          qkv, vT, yb + (size_t)b * 2048 * 1024);
    }
    gemm_fused<<<dim3(8, 32), 256, 0, stream>>>(
        yb, 0, &flags[1], Wproj, &flags[0], 0, bproj, proj, (u16*)nullptr, 0,
        cost, sint, 1024, 1024);
    store_out<<<dim3(2048), 256, 0, stream>>>(proj, d_out, &flags[0]);
  }
}